// Round 3
// baseline (129.878 us; speedup 1.0000x reference)
//
#include <hip/hip_runtime.h>
#include <cstdint>
#include <cstring>

// ============================================================================
// NUTS on diagonal Gaussian, exact JAX-semantics replication.
//
// R2 -> R3 changes (theory: k_traj mode0 still ~2-3x over VALU floor; the
// register near-stack in a fully-unrolled 31-leaf body either spills or
// thrashes I-cache):
//  * mode0 near-stack moved to LDS ([lvl][t/r][d][tid], lane-stride 4B =
//    2-way bank aliasing = free). Tree traversal is now a compact RUNTIME
//    loop (no giant unroll); live registers ~40 -> no spill possible.
//  * k_logic kernel removed: k_red also precomputes the 31x128 per-chain
//    threefry uniforms; k_traj1 runs the unrolled state machine inline
//    (wave-uniform) and early-exits the trajectory at the selected leaf.
//  * 3 launches total: k_traj0 -> k_red -> k_traj1.
// ============================================================================

#define PARTITIONABLE 1

constexpr int NCHAIN = 128;
constexpr int NDIM   = 16384;
constexpr int VD     = 4;                    // dims per thread (one float4)
constexpr int TPB    = 256;
constexpr int WGPC   = NDIM / (TPB * VD);    // 16 workgroups per chain
constexpr int NW     = NDIM / (64 * VD);     // 64 wave-slices per chain
constexpr int NSLOT  = 62;                   // 2*(26 nodes) + 2*(5 doublings)
constexpr int NNODE  = 26;
constexpr int NKEY   = NNODE + 5;            // node keys + accept keys
constexpr float EPS  = 0.05f;

static_assert(NDIM % (TPB * VD) == 0, "tiling");

// ---------------------------------------------------------------- threefry --
__host__ __device__ static inline void tf2(uint32_t k0, uint32_t k1,
                                           uint32_t x0, uint32_t x1,
                                           uint32_t& o0, uint32_t& o1) {
  const uint32_t ks2 = k0 ^ k1 ^ 0x1BD11BDAu;
  x0 += k0; x1 += k1;
#define TF_R(r) { x0 += x1; x1 = (x1 << (r)) | (x1 >> (32 - (r))); x1 ^= x0; }
  TF_R(13) TF_R(15) TF_R(26) TF_R(6)
  x0 += k1;  x1 += ks2 + 1u;
  TF_R(17) TF_R(29) TF_R(16) TF_R(24)
  x0 += ks2; x1 += k0 + 2u;
  TF_R(13) TF_R(15) TF_R(26) TF_R(6)
  x0 += k0;  x1 += k1 + 3u;
  TF_R(17) TF_R(29) TF_R(16) TF_R(24)
  x0 += k1;  x1 += ks2 + 4u;
  TF_R(13) TF_R(15) TF_R(26) TF_R(6)
  x0 += ks2; x1 += k0 + 5u;
#undef TF_R
  o0 = x0; o1 = x1;
}

// uniform [0,1) from 32 random bits, JAX recipe
__device__ static inline float u01(uint32_t bits) {
  return __uint_as_float((bits >> 9) | 0x3f800000u) - 1.0f;
}

// XLA ErfInv32 (Giles), fma-exact
__device__ static inline float erfinv32(float x) {
  float w = -log1pf(-x * x);
  float p;
  if (w < 5.0f) {
    w -= 2.5f;
    p = 2.81022636e-08f;
    p = fmaf(p, w, 3.43273939e-07f);
    p = fmaf(p, w, -3.5233877e-06f);
    p = fmaf(p, w, -4.39150654e-06f);
    p = fmaf(p, w, 0.00021858087f);
    p = fmaf(p, w, -0.00125372503f);
    p = fmaf(p, w, -0.00417768164f);
    p = fmaf(p, w, 0.246640727f);
    p = fmaf(p, w, 1.50140941f);
  } else {
    w = sqrtf(w) - 3.0f;
    p = -0.000200214257f;
    p = fmaf(p, w, 0.000100950558f);
    p = fmaf(p, w, 0.00134934322f);
    p = fmaf(p, w, -0.00367342844f);
    p = fmaf(p, w, 0.00573950773f);
    p = fmaf(p, w, -0.0076224613f);
    p = fmaf(p, w, 0.00943887047f);
    p = fmaf(p, w, 1.00167406f);
    p = fmaf(p, w, 2.83297682f);
  }
  return p * x;
}

// jax.random.normal: u = uniform(lo=nextafter(-1,0), hi=1); hi-lo == 2.0f exactly
__device__ static inline float norm_from_bits(uint32_t bits) {
  const float lo = __uint_as_float(0xBF7FFFFFu);       // -(1 - 2^-24)
  float u = fmaxf(lo, fmaf(u01(bits), 2.0f, lo));
  return __uint_as_float(0x3FB504F3u) * erfinv32(u);   // sqrt(2) in f32
}

// r0 normal for flat element index i of jax.random.normal(kr, (B,D))
__device__ static inline float r0_elem(uint32_t k0, uint32_t k1, uint32_t i) {
#if PARTITIONABLE
  uint32_t a, c; tf2(k0, k1, 0u, i, a, c);
  return norm_from_bits(a ^ c);
#else
  const uint32_t H = (uint32_t)(NCHAIN * NDIM / 2);
  uint32_t a, c;
  if (i < H) { tf2(k0, k1, i, i + H, a, c); return norm_from_bits(a); }
  else       { tf2(k0, k1, i - H, i, a, c); return norm_from_bits(c); }
#endif
}

// one uniform[0,1) for chain b from a (B=128,)-shaped jax.random.uniform
__device__ static inline float unif_chain(uint32_t k0, uint32_t k1, int b) {
#if PARTITIONABLE
  uint32_t a, c; tf2(k0, k1, 0u, (uint32_t)b, a, c);
  return u01(a ^ c);
#else
  uint32_t a, c;
  if (b < 64) { tf2(k0, k1, (uint32_t)b, (uint32_t)(b + 64), a, c); return u01(a); }
  else        { tf2(k0, k1, (uint32_t)(b - 64), (uint32_t)b, a, c); return u01(c); }
#endif
}

// ------------------------------------------------- DPP 64-lane sum (lane 63)
#define DPP_ADD(x, ctrl, rm)                                                   \
  (x) += __int_as_float(__builtin_amdgcn_update_dpp(                           \
      0, __float_as_int(x), (ctrl), (rm), 0xf, true));

__device__ static inline float wave_sum63(float x) {
  DPP_ADD(x, 0x111, 0xf)   // row_shr:1
  DPP_ADD(x, 0x112, 0xf)   // row_shr:2
  DPP_ADD(x, 0x114, 0xf)   // row_shr:4
  DPP_ADD(x, 0x118, 0xf)   // row_shr:8
  DPP_ADD(x, 0x142, 0xa)   // row_bcast:15 -> rows 1,3
  DPP_ADD(x, 0x143, 0xc)   // row_bcast:31 -> rows 2,3
  return x;                // lane 63 holds the 64-lane sum
}

// ------------------------------------------------------------------ params --
struct TrajParams { int v[5]; };
struct KeyParams  { uint32_t k0[NKEY], k1[NKEY]; };  // [0..25] nodes, [26..30] ka

// ----------------------------------------------- K1: trajectory, dots mode --
__launch_bounds__(TPB, 4)
__global__ void k_traj0(const float* __restrict__ th0g, const float* __restrict__ precg,
                        uint32_t kr0, uint32_t kr1,
                        float* __restrict__ partials, TrajParams P) {
  // LDS near-stack: [level][theta/r][dim][tid]; lane stride 4B => conflict-free
  __shared__ float stk[5][2][VD][TPB];
  const int tid     = threadIdx.x;
  const int chain   = blockIdx.x / WGPC;
  const int sblk    = blockIdx.x % WGPC;
  const int dimBase = sblk * (TPB * VD) + tid * VD;
  const int lane    = tid & 63;
  const int wv      = sblk * (TPB / 64) + (tid >> 6);
  const uint32_t flat = (uint32_t)chain * NDIM + dimBase;

  float tha[VD], ra[VD], tho[VD], ro[VD], pc[VD];
  {
    const float4 t = *reinterpret_cast<const float4*>(th0g + (size_t)chain * NDIM + dimBase);
    const float4 p = *reinterpret_cast<const float4*>(precg + dimBase);
    tha[0]=t.x; tha[1]=t.y; tha[2]=t.z; tha[3]=t.w;
    pc [0]=p.x; pc [1]=p.y; pc [2]=p.z; pc [3]=p.w;
  }
#pragma unroll
  for (int d = 0; d < VD; ++d) ra[d] = r0_elem(kr0, kr1, flat + (uint32_t)d);
#pragma unroll
  for (int d = 0; d < VD; ++d) { tho[d] = tha[d]; ro[d] = ra[d]; }

  int slot = 0;
  bool cur_fwd = true;

  for (int j = 0; j < 5; ++j) {
    const bool fwd = P.v[j] > 0;
    if (fwd != cur_fwd) {
#pragma unroll
      for (int d = 0; d < VD; ++d) {
        float t;
        t = tha[d]; tha[d] = tho[d]; tho[d] = t;
        t = ra[d];  ra[d]  = ro[d];  ro[d]  = t;
      }
    }
    cur_fwd = fwd;
    const float e  = fwd ? EPS : -EPS;
    const float he = 0.5f * e;
    const int NL = 1 << j;
    for (int i = 0; i < NL; ++i) {
      // leapfrog step on the active endpoint (grad U = prec * theta)
#pragma unroll
      for (int d = 0; d < VD; ++d) {
        ra[d]  = fmaf(-he, pc[d] * tha[d], ra[d]);
        tha[d] = fmaf(e, ra[d], tha[d]);
        ra[d]  = fmaf(-he, pc[d] * tha[d], ra[d]);
      }
      const int p = __builtin_popcount((unsigned)i);   // push level
#pragma unroll
      for (int d = 0; d < VD; ++d) {
        stk[p][0][d][tid] = tha[d];
        stk[p][1][d][tid] = ra[d];
      }
      const int m = __builtin_ctz(~(unsigned)i);       // merges after this leaf
      for (int k = 0; k < m; ++k) {
        const int s1 = p - 1 - k;                      // near snapshot level
        float d1 = 0.f, d2 = 0.f;
#pragma unroll
        for (int d = 0; d < VD; ++d) {
          float tn = stk[s1][0][d][tid];
          float rn = stk[s1][1][d][tid];
          float dd = tha[d] - tn;
          d1 = fmaf(dd, rn, d1);                       // (th_far-th_near)·r_near
          d2 = fmaf(dd, ra[d], d2);                    // (th_far-th_near)·r_far
        }
        d1 = wave_sum63(d1);
        d2 = wave_sum63(d2);
        if (lane == 63) {
          partials[((size_t)(slot    ) * NCHAIN + chain) * NW + wv] = d1;
          partials[((size_t)(slot + 1) * NCHAIN + chain) * NW + wv] = d2;
        }
        slot += 2;
      }
    }
    // main-loop u-turn raw dots: p1=(a-o)·r_a, p2=(a-o)·r_o; logic maps by v_j
    float p1 = 0.f, p2 = 0.f;
#pragma unroll
    for (int d = 0; d < VD; ++d) {
      float dd = tha[d] - tho[d];
      p1 = fmaf(dd, ra[d], p1);
      p2 = fmaf(dd, ro[d], p2);
    }
    p1 = wave_sum63(p1);
    p2 = wave_sum63(p2);
    if (lane == 63) {
      partials[((size_t)(slot    ) * NCHAIN + chain) * NW + wv] = p1;
      partials[((size_t)(slot + 1) * NCHAIN + chain) * NW + wv] = p2;
    }
    slot += 2;
  }
}

// --------------------------- K_red: fold NW partials + precompute uniforms --
__global__ void k_red(const float* __restrict__ partials, float* __restrict__ dots,
                      float* __restrict__ unifs, KeyParams P) {
  int gid  = blockIdx.x * blockDim.x + threadIdx.x;
  int w    = gid >> 6;                                 // (slot*NCHAIN + b)
  int lane = gid & 63;
  if (w < NSLOT * NCHAIN) {
    float v = partials[(size_t)w * NW + lane];
    v = wave_sum63(v);
    if (lane == 63) dots[w] = v;
  }
  if (gid < NKEY * NCHAIN) {                           // 31*128 = 3968
    int key = gid >> 7, b = gid & 127;
    unifs[gid] = unif_chain(P.k0[key], P.k1[key], b);
  }
}

// --------------------- K3: inline state machine + selective re-simulation ---
__launch_bounds__(TPB, 4)
__global__ void k_traj1(const float* __restrict__ th0g, const float* __restrict__ precg,
                        uint32_t kr0, uint32_t kr1,
                        const float* __restrict__ dots, const float* __restrict__ unifs,
                        float* __restrict__ outg, TrajParams P) {
  const int chain   = blockIdx.x / WGPC;
  const int sblk    = blockIdx.x % WGPC;
  const int dimBase = sblk * (TPB * VD) + threadIdx.x * VD;
  const uint32_t flat = (uint32_t)chain * NDIM + dimBase;

  // ---- NUTS state machine (wave-uniform, fully unrolled so stacks SROA) ----
  int sel = -1;
  {
    int n = 1, s = 1;
    int slot = 0, nodeidx = 0, g = 0;
    int st_n[6], st_s[6], st_p[6];
#pragma unroll
    for (int j = 0; j < 5; ++j) {
      const float vj = (P.v[j] > 0) ? 1.0f : -1.0f;
      const int NL = 1 << j;
      int sp = 0;
#pragma unroll
      for (int i = 0; i < NL; ++i) {
        st_n[sp] = 1; st_s[sp] = 1; st_p[sp] = g; sp++; g++;
        const int m = __builtin_ctz(~(unsigned)i);
#pragma unroll
        for (int k = 0; k < m; ++k) {
          int n1 = st_n[sp-2], s1 = st_s[sp-2], p1i = st_p[sp-2];
          int n2 = st_n[sp-1], s2 = st_s[sp-1], p2i = st_p[sp-1];
          float d1 = dots[(size_t)(slot    ) * NCHAIN + chain];
          float d2 = dots[(size_t)(slot + 1) * NCHAIN + chain];
          slot += 2;
          float uu = unifs[(size_t)nodeidx * NCHAIN + chain];
          nodeidx++;
          int  dn   = n1 + n2; if (dn < 1) dn = 1;
          bool flag = (uu < (float)n2 / (float)dn) && (s1 >= 1);
          int  pm   = flag ? p2i : p1i;
          int  sm   = (s1 != 0 && s2 != 0 &&
                       (vj * d1 >= 0.0f) && (vj * d2 >= 0.0f)) ? 1 : 0;
          int  nm   = n1 + ((s1 >= 1) ? n2 : 0);
          st_n[sp-2] = nm; st_s[sp-2] = sm; st_p[sp-2] = pm;
          sp--;
        }
      }
      int n_p = st_n[0], s_p = st_s[0], th_p = st_p[0];
      float q1 = dots[(size_t)(slot    ) * NCHAIN + chain];   // (a-o)·r_a
      float q2 = dots[(size_t)(slot + 1) * NCHAIN + chain];   // (a-o)·r_o
      slot += 2;
      float dm1, dm2;                                         // d=(th_f - th_r)
      if (P.v[j] > 0) { dm1 = q2;  dm2 = q1; }
      else            { dm1 = -q1; dm2 = -q2; }
      float au = unifs[(size_t)(NNODE + j) * NCHAIN + chain];
      float ratio = fminf((float)n_p / (float)n, 1.0f);
      bool acc = (au < ratio) && (s >= 1) && (s_p >= 1);
      if (acc) sel = th_p;
      n = n + ((s >= 1) ? n_p : 0);
      s = (s != 0 && s_p != 0 && (dm1 >= 0.0f) && (dm2 >= 0.0f)) ? 1 : 0;
    }
  }

  // ---- selective re-simulation: stop at the selected leaf ------------------
  float tha[VD], ra[VD], tho[VD], ro[VD], pc[VD], outv[VD];
  {
    const float4 t = *reinterpret_cast<const float4*>(th0g + (size_t)chain * NDIM + dimBase);
    const float4 p = *reinterpret_cast<const float4*>(precg + dimBase);
    tha[0]=t.x; tha[1]=t.y; tha[2]=t.z; tha[3]=t.w;
    pc [0]=p.x; pc [1]=p.y; pc [2]=p.z; pc [3]=p.w;
  }
#pragma unroll
  for (int d = 0; d < VD; ++d) outv[d] = tha[d];       // default: theta0
  if (sel >= 0) {
#pragma unroll
    for (int d = 0; d < VD; ++d) ra[d] = r0_elem(kr0, kr1, flat + (uint32_t)d);
#pragma unroll
    for (int d = 0; d < VD; ++d) { tho[d] = tha[d]; ro[d] = ra[d]; }
    int g = 0;
    bool cur_fwd = true;
    bool done = false;
    for (int j = 0; j < 5 && !done; ++j) {
      const bool fwd = P.v[j] > 0;
      if (fwd != cur_fwd) {
#pragma unroll
        for (int d = 0; d < VD; ++d) {
          float t;
          t = tha[d]; tha[d] = tho[d]; tho[d] = t;
          t = ra[d];  ra[d]  = ro[d];  ro[d]  = t;
        }
      }
      cur_fwd = fwd;
      const float e  = fwd ? EPS : -EPS;
      const float he = 0.5f * e;
      const int NL = 1 << j;
      for (int i = 0; i < NL; ++i) {
#pragma unroll
        for (int d = 0; d < VD; ++d) {
          ra[d]  = fmaf(-he, pc[d] * tha[d], ra[d]);
          tha[d] = fmaf(e, ra[d], tha[d]);
          ra[d]  = fmaf(-he, pc[d] * tha[d], ra[d]);
        }
        if (g == sel) {
#pragma unroll
          for (int d = 0; d < VD; ++d) outv[d] = tha[d];
          done = true;
          break;
        }
        g++;
      }
    }
  }
  float4 o; o.x = outv[0]; o.y = outv[1]; o.z = outv[2]; o.w = outv[3];
  *reinterpret_cast<float4*>(outg + (size_t)chain * NDIM + dimBase) = o;
}

// ------------------------------------------------------------- host PRNG ---
static inline float host_bits_to_f(uint32_t fb) { float f; std::memcpy(&f, &fb, 4); return f; }

static void host_split(uint32_t k0, uint32_t k1, int nsub, uint32_t* o0, uint32_t* o1) {
#if PARTITIONABLE
  for (int i = 0; i < nsub; ++i) tf2(k0, k1, 0u, (uint32_t)i, o0[i], o1[i]);
#else
  uint32_t A[8], C[8], flat[16];
  for (int i = 0; i < nsub; ++i) tf2(k0, k1, (uint32_t)i, (uint32_t)(nsub + i), A[i], C[i]);
  for (int i = 0; i < nsub; ++i) { flat[i] = A[i]; flat[nsub + i] = C[i]; }
  for (int j = 0; j < nsub; ++j) { o0[j] = flat[2*j]; o1[j] = flat[2*j + 1]; }
#endif
}

static int host_vsign(uint32_t k0, uint32_t k1) {    // sign of normal(kv, ())
  uint32_t a, c; tf2(k0, k1, 0u, 0u, a, c);
#if PARTITIONABLE
  uint32_t bits = a ^ c;
#else
  uint32_t bits = a;
#endif
  float f  = host_bits_to_f((bits >> 9) | 0x3f800000u) - 1.0f;
  float lo = host_bits_to_f(0xBF7FFFFFu);
  float u  = f * 2.0f + lo;                          // sign(erfinv(u)) = sign(u)
  return (u >= 0.0f) ? 1 : -1;
}

// buildtree k3 keys in post-order (merge-consumption order)
static void gen_nodes(uint32_t k0, uint32_t k1, int j,
                      uint32_t* nk0, uint32_t* nk1, int& idx) {
  if (j == 0) return;
  uint32_t o0[3], o1[3];
  host_split(k0, k1, 3, o0, o1);                     // k1, k2, k3
  gen_nodes(o0[0], o1[0], j - 1, nk0, nk1, idx);
  gen_nodes(o0[1], o1[1], j - 1, nk0, nk1, idx);
  nk0[idx] = o0[2]; nk1[idx] = o1[2]; idx++;
}

// ---------------------------------------------------------------- launch ----
extern "C" void kernel_launch(void* const* d_in, const int* in_sizes, int n_in,
                              void* d_out, int out_size, void* d_ws, size_t ws_size,
                              hipStream_t stream) {
  const float* th0  = (const float*)d_in[0];
  const float* prec = (const float*)d_in[1];
  float* out = (float*)d_out;

  float* partials = (float*)d_ws;                               // ~2 MB
  float* dots     = partials + (size_t)NSLOT * NCHAIN * NW;     // ~32 KB
  float* unifs    = dots + (size_t)NSLOT * NCHAIN;              // ~16 KB

  // ---- replicate jax key schedule on host (deterministic, same every call)
  uint32_t key0 = 0u, key1 = 42u;                               // jax.random.key(42)
  uint32_t s0[4], s1[4];
  host_split(key0, key1, 3, s0, s1);                            // kr, ku, key
  const uint32_t kr0 = s0[0], kr1 = s1[0];                      // r0 normals
  key0 = s0[2]; key1 = s1[2];                                   // (ku unused: u==0)

  KeyParams PK; TrajParams PT;
  int idx = 0;
  for (int j = 0; j < 5; ++j) {
    host_split(key0, key1, 4, s0, s1);                          // key, kv, kt, ka
    key0 = s0[0]; key1 = s1[0];
    PT.v[j] = host_vsign(s0[1], s1[1]);
    gen_nodes(s0[2], s1[2], j, PK.k0, PK.k1, idx);              // kt recursion
    PK.k0[NNODE + j] = s0[3]; PK.k1[NNODE + j] = s1[3];         // ka
  }

  // ---- K1: trajectory + dot partials (r0 generated inline)
  k_traj0<<<dim3(NCHAIN * WGPC), dim3(TPB), 0, stream>>>(
      th0, prec, kr0, kr1, partials, PT);
  // ---- fold partials + precompute per-chain uniforms
  k_red<<<dim3((NSLOT * NCHAIN * 64) / TPB), dim3(TPB), 0, stream>>>(
      partials, dots, unifs, PK);
  // ---- state machine inline + selective re-simulation
  k_traj1<<<dim3(NCHAIN * WGPC), dim3(TPB), 0, stream>>>(
      th0, prec, kr0, kr1, dots, unifs, out, PT);
}

// Round 4
// 123.562 us; speedup vs baseline: 1.0511x; 1.0511x over previous
//
#include <hip/hip_runtime.h>
#include <cstdint>
#include <cstring>

// ============================================================================
// NUTS on diagonal Gaussian, exact JAX-semantics replication.
//
// R3 -> R4 changes (theory: all trajectory kernels were scratch-bound via
// runtime-indexed local arrays; compiler refused to fully unroll the 31-leaf
// nested loop so the near-stack indices stayed runtime -> spills; R3's
// k_traj1 state machine had runtime 'sp' -> scratch, VGPR=20):
//  * k_traj0 tree is unrolled by TEMPLATE RECURSION over leaves: popcount/
//    ctz indices are constexpr, near-stack is compile-time indexed ->
//    guaranteed register promotion. __launch_bounds__(256,2) lifts VGPR cap.
//  * state machine back in a tiny separate kernel (128 threads; its cost is
//    irrelevant); k_gather reads sel[chain] and has NO local arrays.
//  * 4 launches: k_traj0 -> k_red -> k_logic -> k_gather.
// ============================================================================

#define PARTITIONABLE 1

constexpr int NCHAIN = 128;
constexpr int NDIM   = 16384;
constexpr int VD     = 4;                    // dims per thread (one float4)
constexpr int TPB    = 256;
constexpr int WGPC   = NDIM / (TPB * VD);    // 16 workgroups per chain
constexpr int NW     = NDIM / (64 * VD);     // 64 wave-slices per chain
constexpr int NSLOT  = 62;                   // 2*(26 nodes) + 2*(5 doublings)
constexpr int NNODE  = 26;
constexpr float EPS  = 0.05f;

static_assert(NDIM % (TPB * VD) == 0, "tiling");

// ---------------------------------------------------------------- threefry --
__host__ __device__ static inline void tf2(uint32_t k0, uint32_t k1,
                                           uint32_t x0, uint32_t x1,
                                           uint32_t& o0, uint32_t& o1) {
  const uint32_t ks2 = k0 ^ k1 ^ 0x1BD11BDAu;
  x0 += k0; x1 += k1;
#define TF_R(r) { x0 += x1; x1 = (x1 << (r)) | (x1 >> (32 - (r))); x1 ^= x0; }
  TF_R(13) TF_R(15) TF_R(26) TF_R(6)
  x0 += k1;  x1 += ks2 + 1u;
  TF_R(17) TF_R(29) TF_R(16) TF_R(24)
  x0 += ks2; x1 += k0 + 2u;
  TF_R(13) TF_R(15) TF_R(26) TF_R(6)
  x0 += k0;  x1 += k1 + 3u;
  TF_R(17) TF_R(29) TF_R(16) TF_R(24)
  x0 += k1;  x1 += ks2 + 4u;
  TF_R(13) TF_R(15) TF_R(26) TF_R(6)
  x0 += ks2; x1 += k0 + 5u;
#undef TF_R
  o0 = x0; o1 = x1;
}

// uniform [0,1) from 32 random bits, JAX recipe
__device__ static inline float u01(uint32_t bits) {
  return __uint_as_float((bits >> 9) | 0x3f800000u) - 1.0f;
}

// XLA ErfInv32 (Giles), fma-exact
__device__ static inline float erfinv32(float x) {
  float w = -log1pf(-x * x);
  float p;
  if (w < 5.0f) {
    w -= 2.5f;
    p = 2.81022636e-08f;
    p = fmaf(p, w, 3.43273939e-07f);
    p = fmaf(p, w, -3.5233877e-06f);
    p = fmaf(p, w, -4.39150654e-06f);
    p = fmaf(p, w, 0.00021858087f);
    p = fmaf(p, w, -0.00125372503f);
    p = fmaf(p, w, -0.00417768164f);
    p = fmaf(p, w, 0.246640727f);
    p = fmaf(p, w, 1.50140941f);
  } else {
    w = sqrtf(w) - 3.0f;
    p = -0.000200214257f;
    p = fmaf(p, w, 0.000100950558f);
    p = fmaf(p, w, 0.00134934322f);
    p = fmaf(p, w, -0.00367342844f);
    p = fmaf(p, w, 0.00573950773f);
    p = fmaf(p, w, -0.0076224613f);
    p = fmaf(p, w, 0.00943887047f);
    p = fmaf(p, w, 1.00167406f);
    p = fmaf(p, w, 2.83297682f);
  }
  return p * x;
}

// jax.random.normal: u = uniform(lo=nextafter(-1,0), hi=1); hi-lo == 2.0f exactly
__device__ static inline float norm_from_bits(uint32_t bits) {
  const float lo = __uint_as_float(0xBF7FFFFFu);       // -(1 - 2^-24)
  float u = fmaxf(lo, fmaf(u01(bits), 2.0f, lo));
  return __uint_as_float(0x3FB504F3u) * erfinv32(u);   // sqrt(2) in f32
}

// r0 normal for flat element index i of jax.random.normal(kr, (B,D))
__device__ static inline float r0_elem(uint32_t k0, uint32_t k1, uint32_t i) {
#if PARTITIONABLE
  uint32_t a, c; tf2(k0, k1, 0u, i, a, c);
  return norm_from_bits(a ^ c);
#else
  const uint32_t H = (uint32_t)(NCHAIN * NDIM / 2);
  uint32_t a, c;
  if (i < H) { tf2(k0, k1, i, i + H, a, c); return norm_from_bits(a); }
  else       { tf2(k0, k1, i - H, i, a, c); return norm_from_bits(c); }
#endif
}

// one uniform[0,1) for chain b from a (B=128,)-shaped jax.random.uniform
__device__ static inline float unif_chain(uint32_t k0, uint32_t k1, int b) {
#if PARTITIONABLE
  uint32_t a, c; tf2(k0, k1, 0u, (uint32_t)b, a, c);
  return u01(a ^ c);
#else
  uint32_t a, c;
  if (b < 64) { tf2(k0, k1, (uint32_t)b, (uint32_t)(b + 64), a, c); return u01(a); }
  else        { tf2(k0, k1, (uint32_t)(b - 64), (uint32_t)b, a, c); return u01(c); }
#endif
}

// ------------------------------------------------- DPP 64-lane sum (lane 63)
#define DPP_ADD(x, ctrl, rm)                                                   \
  (x) += __int_as_float(__builtin_amdgcn_update_dpp(                           \
      0, __float_as_int(x), (ctrl), (rm), 0xf, true));

__device__ static inline float wave_sum63(float x) {
  DPP_ADD(x, 0x111, 0xf)   // row_shr:1
  DPP_ADD(x, 0x112, 0xf)   // row_shr:2
  DPP_ADD(x, 0x114, 0xf)   // row_shr:4
  DPP_ADD(x, 0x118, 0xf)   // row_shr:8
  DPP_ADD(x, 0x142, 0xa)   // row_bcast:15 -> rows 1,3
  DPP_ADD(x, 0x143, 0xc)   // row_bcast:31 -> rows 2,3
  return x;                // lane 63 holds the 64-lane sum
}

// ------------------------------------------------------------------ params --
struct TrajParams { int v[5]; };
struct K2Params {
  uint32_t nk0[NNODE], nk1[NNODE];  // buildtree k3 keys, post-order across j
  uint32_t ak0[5], ak1[5];          // main-loop ka keys
  int v[5];
};

// --------------------------------------- trajectory state (SROA-friendly) ---
struct St {
  float tha[VD], ra[VD], tho[VD], ro[VD], pc[VD];
  float nt[5][VD], nr[5][VD];       // near-stack: compile-time indexed ONLY
};

// one leaf + its merges; all stack indices constexpr
template <int J, int I>
__device__ __forceinline__ void leaf_body(St& st, const float e, const float he,
                                          float* __restrict__ partials,
                                          const int chain, const int wv,
                                          const int lane, int& slot) {
#pragma unroll
  for (int d = 0; d < VD; ++d) {
    st.ra[d]  = fmaf(-he, st.pc[d] * st.tha[d], st.ra[d]);
    st.tha[d] = fmaf(e, st.ra[d], st.tha[d]);
    st.ra[d]  = fmaf(-he, st.pc[d] * st.tha[d], st.ra[d]);
  }
  constexpr int P = __builtin_popcount((unsigned)I);   // push level
#pragma unroll
  for (int d = 0; d < VD; ++d) { st.nt[P][d] = st.tha[d]; st.nr[P][d] = st.ra[d]; }
  constexpr int M = __builtin_ctz(~(unsigned)I);       // merges after this leaf
#pragma unroll
  for (int k = 0; k < M; ++k) {                        // M<=4, k folds to const
    const int s1 = P - 1 - k;
    float d1 = 0.f, d2 = 0.f;
#pragma unroll
    for (int d = 0; d < VD; ++d) {
      float dd = st.tha[d] - st.nt[s1][d];
      d1 = fmaf(dd, st.nr[s1][d], d1);                 // (th_far-th_near)·r_near
      d2 = fmaf(dd, st.ra[d], d2);                     // (th_far-th_near)·r_far
    }
    d1 = wave_sum63(d1);
    d2 = wave_sum63(d2);
    if (lane == 63) {
      partials[((size_t)(slot    ) * NCHAIN + chain) * NW + wv] = d1;
      partials[((size_t)(slot + 1) * NCHAIN + chain) * NW + wv] = d2;
    }
    slot += 2;
  }
}

template <int J, int I>
__device__ __forceinline__ void run_level(St& st, const float e, const float he,
                                          float* __restrict__ partials,
                                          const int chain, const int wv,
                                          const int lane, int& slot) {
  leaf_body<J, I>(st, e, he, partials, chain, wv, lane, slot);
  if constexpr (I + 1 < (1 << J))
    run_level<J, I + 1>(st, e, he, partials, chain, wv, lane, slot);
}

// ----------------------------------------------- K1: trajectory, dots mode --
__launch_bounds__(TPB, 2)
__global__ void k_traj0(const float* __restrict__ th0g, const float* __restrict__ precg,
                        uint32_t kr0, uint32_t kr1,
                        float* __restrict__ partials, TrajParams P) {
  const int tid     = threadIdx.x;
  const int chain   = blockIdx.x / WGPC;
  const int sblk    = blockIdx.x % WGPC;
  const int dimBase = sblk * (TPB * VD) + tid * VD;
  const int lane    = tid & 63;
  const int wv      = sblk * (TPB / 64) + (tid >> 6);
  const uint32_t flat = (uint32_t)chain * NDIM + dimBase;

  St st;
  {
    const float4 t = *reinterpret_cast<const float4*>(th0g + (size_t)chain * NDIM + dimBase);
    const float4 p = *reinterpret_cast<const float4*>(precg + dimBase);
    st.tha[0]=t.x; st.tha[1]=t.y; st.tha[2]=t.z; st.tha[3]=t.w;
    st.pc [0]=p.x; st.pc [1]=p.y; st.pc [2]=p.z; st.pc [3]=p.w;
  }
#pragma unroll
  for (int d = 0; d < VD; ++d) st.ra[d] = r0_elem(kr0, kr1, flat + (uint32_t)d);
#pragma unroll
  for (int d = 0; d < VD; ++d) { st.tho[d] = st.tha[d]; st.ro[d] = st.ra[d]; }

  int slot = 0;
  bool cur_fwd = true;

#define LEVEL(J)                                                               \
  {                                                                            \
    const bool fwd = P.v[J] > 0;                                               \
    if (fwd != cur_fwd) {                                                      \
      _Pragma("unroll")                                                        \
      for (int d = 0; d < VD; ++d) {                                           \
        float t;                                                               \
        t = st.tha[d]; st.tha[d] = st.tho[d]; st.tho[d] = t;                   \
        t = st.ra[d];  st.ra[d]  = st.ro[d];  st.ro[d]  = t;                   \
      }                                                                        \
    }                                                                          \
    cur_fwd = fwd;                                                             \
    const float e  = fwd ? EPS : -EPS;                                         \
    const float he = 0.5f * e;                                                 \
    run_level<J, 0>(st, e, he, partials, chain, wv, lane, slot);               \
    float p1 = 0.f, p2 = 0.f;                                                  \
    _Pragma("unroll")                                                          \
    for (int d = 0; d < VD; ++d) {                                             \
      float dd = st.tha[d] - st.tho[d];                                        \
      p1 = fmaf(dd, st.ra[d], p1);                                             \
      p2 = fmaf(dd, st.ro[d], p2);                                             \
    }                                                                          \
    p1 = wave_sum63(p1);                                                       \
    p2 = wave_sum63(p2);                                                       \
    if (lane == 63) {                                                          \
      partials[((size_t)(slot    ) * NCHAIN + chain) * NW + wv] = p1;          \
      partials[((size_t)(slot + 1) * NCHAIN + chain) * NW + wv] = p2;          \
    }                                                                          \
    slot += 2;                                                                 \
  }

  LEVEL(0) LEVEL(1) LEVEL(2) LEVEL(3) LEVEL(4)
#undef LEVEL
}

// ------------------------------------------------ K_red: fold NW partials ---
__global__ void k_red(const float* __restrict__ partials, float* __restrict__ dots) {
  int gid  = blockIdx.x * blockDim.x + threadIdx.x;
  int w    = gid >> 6;                                 // (slot*NCHAIN + b)
  int lane = gid & 63;
  if (w >= NSLOT * NCHAIN) return;
  float v = partials[(size_t)w * NW + lane];
  v = wave_sum63(v);
  if (lane == 63) dots[w] = v;
}

// ---------------------------------------- K2: per-chain NUTS state machine --
__global__ void k_logic(const float* __restrict__ dots, int* __restrict__ selg,
                        K2Params P) {
  int b = threadIdx.x;
  if (b >= NCHAIN) return;
  int n = 1, s = 1, sel = -1;
  int slot = 0, nodeidx = 0, g = 0;
  int st_n[6], st_s[6], st_p[6];
  for (int j = 0; j < 5; ++j) {
    float vj = (P.v[j] > 0) ? 1.0f : -1.0f;
    int sp = 0;
    int NL = 1 << j;
    for (int i = 0; i < NL; ++i) {
      st_n[sp] = 1; st_s[sp] = 1; st_p[sp] = g; sp++; g++;   // leaf: n=1,s=1
      int m = __builtin_ctz(~(unsigned)i);
      for (int k = 0; k < m; ++k) {
        int n1 = st_n[sp-2], s1 = st_s[sp-2], p1i = st_p[sp-2];
        int n2 = st_n[sp-1], s2 = st_s[sp-1], p2i = st_p[sp-1];
        float d1 = dots[(size_t)(slot    ) * NCHAIN + b];
        float d2 = dots[(size_t)(slot + 1) * NCHAIN + b];
        slot += 2;
        float uu = unif_chain(P.nk0[nodeidx], P.nk1[nodeidx], b);
        nodeidx++;
        int   dn    = n1 + n2; if (dn < 1) dn = 1;
        bool  flag  = (uu < (float)n2 / (float)dn) && (s1 >= 1);
        int   pm    = flag ? p2i : p1i;
        int   sm    = (s1 != 0 && s2 != 0 &&
                       (vj * d1 >= 0.0f) && (vj * d2 >= 0.0f)) ? 1 : 0;
        int   nm    = n1 + ((s1 >= 1) ? n2 : 0);
        st_n[sp-2] = nm; st_s[sp-2] = sm; st_p[sp-2] = pm;
        sp--;
      }
    }
    int n_p = st_n[0], s_p = st_s[0], th_p = st_p[0];
    float q1 = dots[(size_t)(slot    ) * NCHAIN + b];   // (a-o)·r_a
    float q2 = dots[(size_t)(slot + 1) * NCHAIN + b];   // (a-o)·r_o
    slot += 2;
    float dm1, dm2;                                     // d=(th_f - th_r)
    if (P.v[j] > 0) { dm1 = q2;  dm2 = q1; }            // active endpoint = fwd
    else            { dm1 = -q1; dm2 = -q2; }           // active endpoint = bwd
    float au = unif_chain(P.ak0[j], P.ak1[j], b);
    float ratio = fminf((float)n_p / (float)n, 1.0f);
    bool acc = (au < ratio) && (s >= 1) && (s_p >= 1);
    if (acc) sel = th_p;
    n = n + ((s >= 1) ? n_p : 0);
    s = (s != 0 && s_p != 0 && (dm1 >= 0.0f) && (dm2 >= 0.0f)) ? 1 : 0;
  }
  selg[b] = sel;
}

// -------------------- K3: gather — re-simulate to the selected leaf, write --
__launch_bounds__(TPB, 2)
__global__ void k_gather(const float* __restrict__ th0g, const float* __restrict__ precg,
                         uint32_t kr0, uint32_t kr1,
                         const int* __restrict__ selg, float* __restrict__ outg,
                         TrajParams P) {
  const int chain   = blockIdx.x / WGPC;
  const int sblk    = blockIdx.x % WGPC;
  const int dimBase = sblk * (TPB * VD) + threadIdx.x * VD;
  const uint32_t flat = (uint32_t)chain * NDIM + dimBase;
  const int sel = selg[chain];                         // wave-uniform

  float tha[VD], ra[VD], tho[VD], ro[VD], pc[VD], outv[VD];
  {
    const float4 t = *reinterpret_cast<const float4*>(th0g + (size_t)chain * NDIM + dimBase);
    const float4 p = *reinterpret_cast<const float4*>(precg + dimBase);
    tha[0]=t.x; tha[1]=t.y; tha[2]=t.z; tha[3]=t.w;
    pc [0]=p.x; pc [1]=p.y; pc [2]=p.z; pc [3]=p.w;
  }
#pragma unroll
  for (int d = 0; d < VD; ++d) outv[d] = tha[d];       // default: theta0
  if (sel >= 0) {
#pragma unroll
    for (int d = 0; d < VD; ++d) ra[d] = r0_elem(kr0, kr1, flat + (uint32_t)d);
#pragma unroll
    for (int d = 0; d < VD; ++d) { tho[d] = tha[d]; ro[d] = ra[d]; }
    int g = 0;
    bool cur_fwd = true;
    bool done = false;
    for (int j = 0; j < 5 && !done; ++j) {
      const bool fwd = P.v[j] > 0;
      if (fwd != cur_fwd) {
#pragma unroll
        for (int d = 0; d < VD; ++d) {
          float t;
          t = tha[d]; tha[d] = tho[d]; tho[d] = t;
          t = ra[d];  ra[d]  = ro[d];  ro[d]  = t;
        }
      }
      cur_fwd = fwd;
      const float e  = fwd ? EPS : -EPS;
      const float he = 0.5f * e;
      const int NL = 1 << j;
      for (int i = 0; i < NL; ++i) {
#pragma unroll
        for (int d = 0; d < VD; ++d) {
          ra[d]  = fmaf(-he, pc[d] * tha[d], ra[d]);
          tha[d] = fmaf(e, ra[d], tha[d]);
          ra[d]  = fmaf(-he, pc[d] * tha[d], ra[d]);
        }
        if (g == sel) {
#pragma unroll
          for (int d = 0; d < VD; ++d) outv[d] = tha[d];
          done = true;
          break;
        }
        g++;
      }
    }
  }
  float4 o; o.x = outv[0]; o.y = outv[1]; o.z = outv[2]; o.w = outv[3];
  *reinterpret_cast<float4*>(outg + (size_t)chain * NDIM + dimBase) = o;
}

// ------------------------------------------------------------- host PRNG ---
static inline float host_bits_to_f(uint32_t fb) { float f; std::memcpy(&f, &fb, 4); return f; }

static void host_split(uint32_t k0, uint32_t k1, int nsub, uint32_t* o0, uint32_t* o1) {
#if PARTITIONABLE
  for (int i = 0; i < nsub; ++i) tf2(k0, k1, 0u, (uint32_t)i, o0[i], o1[i]);
#else
  uint32_t A[8], C[8], flat[16];
  for (int i = 0; i < nsub; ++i) tf2(k0, k1, (uint32_t)i, (uint32_t)(nsub + i), A[i], C[i]);
  for (int i = 0; i < nsub; ++i) { flat[i] = A[i]; flat[nsub + i] = C[i]; }
  for (int j = 0; j < nsub; ++j) { o0[j] = flat[2*j]; o1[j] = flat[2*j + 1]; }
#endif
}

static int host_vsign(uint32_t k0, uint32_t k1) {    // sign of normal(kv, ())
  uint32_t a, c; tf2(k0, k1, 0u, 0u, a, c);
#if PARTITIONABLE
  uint32_t bits = a ^ c;
#else
  uint32_t bits = a;
#endif
  float f  = host_bits_to_f((bits >> 9) | 0x3f800000u) - 1.0f;
  float lo = host_bits_to_f(0xBF7FFFFFu);
  float u  = f * 2.0f + lo;                          // sign(erfinv(u)) = sign(u)
  return (u >= 0.0f) ? 1 : -1;
}

// buildtree k3 keys in post-order (merge-consumption order)
static void gen_nodes(uint32_t k0, uint32_t k1, int j,
                      uint32_t* nk0, uint32_t* nk1, int& idx) {
  if (j == 0) return;
  uint32_t o0[3], o1[3];
  host_split(k0, k1, 3, o0, o1);                     // k1, k2, k3
  gen_nodes(o0[0], o1[0], j - 1, nk0, nk1, idx);
  gen_nodes(o0[1], o1[1], j - 1, nk0, nk1, idx);
  nk0[idx] = o0[2]; nk1[idx] = o1[2]; idx++;
}

// ---------------------------------------------------------------- launch ----
extern "C" void kernel_launch(void* const* d_in, const int* in_sizes, int n_in,
                              void* d_out, int out_size, void* d_ws, size_t ws_size,
                              hipStream_t stream) {
  const float* th0  = (const float*)d_in[0];
  const float* prec = (const float*)d_in[1];
  float* out = (float*)d_out;

  float* partials = (float*)d_ws;                               // ~2 MB
  float* dots     = partials + (size_t)NSLOT * NCHAIN * NW;     // ~32 KB
  int*   sel      = (int*)(dots + (size_t)NSLOT * NCHAIN);      // 512 B

  // ---- replicate jax key schedule on host (deterministic, same every call)
  uint32_t key0 = 0u, key1 = 42u;                               // jax.random.key(42)
  uint32_t s0[4], s1[4];
  host_split(key0, key1, 3, s0, s1);                            // kr, ku, key
  const uint32_t kr0 = s0[0], kr1 = s1[0];                      // r0 normals
  key0 = s0[2]; key1 = s1[2];                                   // (ku unused: u==0)

  K2Params P2; TrajParams PT;
  int idx = 0;
  for (int j = 0; j < 5; ++j) {
    host_split(key0, key1, 4, s0, s1);                          // key, kv, kt, ka
    key0 = s0[0]; key1 = s1[0];
    int v = host_vsign(s0[1], s1[1]);
    P2.v[j] = v; PT.v[j] = v;
    gen_nodes(s0[2], s1[2], j, P2.nk0, P2.nk1, idx);            // kt recursion
    P2.ak0[j] = s0[3]; P2.ak1[j] = s1[3];                       // ka
  }

  // ---- K1: trajectory + dot partials (r0 generated inline)
  k_traj0<<<dim3(NCHAIN * WGPC), dim3(TPB), 0, stream>>>(
      th0, prec, kr0, kr1, partials, PT);
  // ---- fold partials (62*128 waves, 64 values each)
  k_red<<<dim3((NSLOT * NCHAIN * 64) / TPB), dim3(TPB), 0, stream>>>(partials, dots);
  // ---- per-chain state machine -> selected leaf index
  k_logic<<<dim3(1), dim3(NCHAIN), 0, stream>>>(dots, sel, P2);
  // ---- gather: re-simulate to selected leaf, write (all chains)
  k_gather<<<dim3(NCHAIN * WGPC), dim3(TPB), 0, stream>>>(
      th0, prec, kr0, kr1, sel, out, PT);
}